// Round 6
// baseline (891.053 us; speedup 1.0000x reference)
//
#include <hip/hip_runtime.h>
#include <hip/hip_bf16.h>
#include <stdint.h>

#define T_TOK 4096
#define DIMD  2048
#define NEXP  16
#define TOPK  4
#define NI    1024
#define NSH   2048

typedef __attribute__((ext_vector_type(8))) short short8;
typedef __attribute__((ext_vector_type(4))) float f32x4;
typedef __attribute__((ext_vector_type(4))) unsigned short u16x4;

__device__ __forceinline__ unsigned short f2bf(float f) {
    union { float f; unsigned u; } v; v.f = f;
    return (unsigned short)((v.u + 0x7fffu + ((v.u >> 16) & 1u)) >> 16);
}

__device__ __forceinline__ void gload16(const void* g, void* l) {
    __builtin_amdgcn_global_load_lds(
        (const __attribute__((address_space(1))) void*)g,
        (__attribute__((address_space(3))) void*)l, 16, 0, 0);
}

// ---------------- gw transpose: [2048][16] -> [16][2048] fp32 ----------------
__global__ __launch_bounds__(256) void gwt_kernel(const float* __restrict__ gw,
                                                  float* __restrict__ gwT) {
    int i = blockIdx.x * 256 + threadIdx.x;   // 32768 elements
    int d = i >> 4, e = i & 15;
    gwT[e * DIMD + d] = gw[i];
}

// ---------------- gate + routing (coalesced, reg-resident) ----------------
__global__ __launch_bounds__(256) void gate_kernel(const float* __restrict__ x,
                                                   const float* __restrict__ gwT,
                                                   int* __restrict__ cnt,
                                                   int* __restrict__ list,
                                                   float* __restrict__ cw) {
    const int t = blockIdx.x * 4 + (threadIdx.x >> 6);
    const int lane = threadIdx.x & 63;

    // x row -> 8 f32x4 regs, coalesced (lane-contiguous 16B)
    const f32x4* xr = (const f32x4*)(x + (size_t)t * DIMD);
    f32x4 xv[8];
#pragma unroll
    for (int i = 0; i < 8; ++i) xv[i] = xr[i * 64 + lane];

    float acc[NEXP];
#pragma unroll
    for (int e = 0; e < NEXP; ++e) {
        const f32x4* gr = (const f32x4*)(gwT + e * DIMD);
        float s = 0.f;
#pragma unroll
        for (int i = 0; i < 8; ++i) {
            f32x4 gv = gr[i * 64 + lane];
            s += xv[i][0] * gv[0] + xv[i][1] * gv[1] +
                 xv[i][2] * gv[2] + xv[i][3] * gv[3];
        }
        acc[e] = s;
    }
    // butterfly reduce each expert score across the wave
#pragma unroll
    for (int e = 0; e < NEXP; ++e) {
        float v = acc[e];
#pragma unroll
        for (int off = 32; off; off >>= 1) v += __shfl_xor(v, off, 64);
        acc[e] = v;
    }
    // softmax over 16 (all lanes redundantly, registers only)
    float m = acc[0];
#pragma unroll
    for (int e = 1; e < NEXP; ++e) m = fmaxf(m, acc[e]);
    float s = 0.f;
#pragma unroll
    for (int e = 0; e < NEXP; ++e) { acc[e] = expf(acc[e] - m); s += acc[e]; }
    float inv = 1.f / s;
#pragma unroll
    for (int e = 0; e < NEXP; ++e) acc[e] *= inv;

    // top-4, static indexing only (no scratch): strict > keeps lowest index on tie
    float w4[TOPK]; int i4[TOPK];
#pragma unroll
    for (int k = 0; k < TOPK; ++k) {
        float bv = -1.f; int be = 0;
#pragma unroll
        for (int e = 0; e < NEXP; ++e)
            if (acc[e] > bv) { bv = acc[e]; be = e; }
        w4[k] = bv; i4[k] = be;
#pragma unroll
        for (int e = 0; e < NEXP; ++e)
            if (e == be) acc[e] = -1.f;
    }

    if (lane == 0) {
#pragma unroll
        for (int k = 0; k < TOPK; ++k) {
            int r = atomicAdd(&cnt[i4[k]], 1);
            list[i4[k] * T_TOK + r] = t;
            cw[i4[k] * T_TOK + r] = w4[k];
        }
    }
}

// offsets + compact tile table: table[s]=expert, table[128+s]=rb, table[255]=nslots
__global__ void scan_kernel(const int* __restrict__ cnt, int* __restrict__ offs,
                            int* __restrict__ table) {
    if (threadIdx.x == 0) {
        int o = 0;
        for (int e = 0; e < NEXP; ++e) { offs[e] = o; o += cnt[e]; }
        offs[NEXP] = o;
        int ns = 0;
        for (int e = 0; e < NEXP; ++e)
            for (int rb = 0; rb < cnt[e]; rb += 256) {
                table[ns] = e; table[128 + ns] = rb; ++ns;
            }
        table[255] = ns;
    }
}

// ---------------- x fp32 -> bf16 ----------------
__global__ __launch_bounds__(256) void cvt_kernel(const float* __restrict__ x,
                                                  unsigned short* __restrict__ xb) {
    int i = blockIdx.x * 256 + threadIdx.x;
    const f32x4* src = (const f32x4*)x;
    f32x4 a = src[i * 2 + 0];
    f32x4 b = src[i * 2 + 1];
    short8 o;
#pragma unroll
    for (int j = 0; j < 4; ++j) o[j] = (short)f2bf(a[j]);
#pragma unroll
    for (int j = 0; j < 4; ++j) o[4 + j] = (short)f2bf(b[j]);
    ((short8*)xb)[i] = o;
}

// ---------------- weight transpose + convert ----------------
template <int MODE>
__global__ __launch_bounds__(256) void tq_kernel(const float* __restrict__ src,
                                                 unsigned short* __restrict__ dst,
                                                 int K, int N, size_t dstStrideE) {
    int e = blockIdx.z;
    src += (size_t)e * K * N;
    dst += (size_t)e * dstStrideE;
    __shared__ unsigned short tile[32][36];
    int t = threadIdx.x;
    int k0 = blockIdx.y * 32, n0 = blockIdx.x * 32;
    {
        int row = t >> 3, c4 = (t & 7) * 4;
        f32x4 v = *(const f32x4*)(src + (size_t)(k0 + row) * N + n0 + c4);
#pragma unroll
        for (int j = 0; j < 4; ++j) tile[row][c4 + j] = f2bf(v[j]);
    }
    __syncthreads();
    {
        int nn = t >> 3, kc = (t & 7) * 4;
        int n = n0 + nn;
        int r = (MODE == 0) ? n : ((n >> 4) * 32 + (MODE == 2 ? 16 : 0) + (n & 15));
        u16x4 o;
#pragma unroll
        for (int j = 0; j < 4; ++j) o[j] = tile[kc + j][nn];
        *(u16x4*)(dst + (size_t)r * K + k0 + kc) = o;
    }
}

// ================= 256x256 GEMM, deep pipeline =================
// LDS 160KB: A double-buffer [0,32K),[32K,64K); B triple-buffer 64K+{0,1,2}*32K.
// Per K-tile t: stage A(t+1) (4 loads, phA) and B(t+2) (2+2, phB/phC).
// One wait/tile: vmcnt(4) at phD (newest 4 = B(t+2)); vmcnt(0) for tail tiles.

#define STA4(base, kt) do { \
    gload16(gA[0][0] + (kt) * 64, (void*)(smem + (base) + ldsA[0][0])); \
    gload16(gA[0][1] + (kt) * 64, (void*)(smem + (base) + ldsA[0][1])); \
    gload16(gA[1][0] + (kt) * 64, (void*)(smem + (base) + ldsA[1][0])); \
    gload16(gA[1][1] + (kt) * 64, (void*)(smem + (base) + ldsA[1][1])); \
  } while (0)
#define STBU(base, kt, u) do { \
    gload16(gB[u][0] + (kt) * 64, (void*)(smem + (base) + ldsB[u][0])); \
    gload16(gB[u][1] + (kt) * 64, (void*)(smem + (base) + ldsB[u][1])); \
  } while (0)

#define RDA(base, MH) do { \
    _Pragma("unroll") \
    for (int m2 = 0; m2 < 4; ++m2) { \
      const char* bp = smem + (base) + (wm * 128 + (MH) * 64 + m2 * 16 + fr) * 128; \
      aF[m2][0] = *(const short8*)(bp + kA0); \
      aF[m2][1] = *(const short8*)(bp + kA1); \
    } } while (0)
#define RDB(dst, base, NH) do { \
    _Pragma("unroll") \
    for (int n2 = 0; n2 < 2; ++n2) { \
      const char* bp = smem + (base) + (wn * 64 + (NH) * 32 + n2 * 16 + fr) * 128; \
      dst[n2][0] = *(const short8*)(bp + kA0); \
      dst[n2][1] = *(const short8*)(bp + kA1); \
    } } while (0)

#define MM(MH, NH, BF) do { \
    __builtin_amdgcn_s_setprio(1); \
    _Pragma("unroll") \
    for (int m2 = 0; m2 < 4; ++m2) { \
      _Pragma("unroll") \
      for (int n2 = 0; n2 < 2; ++n2) { \
        acc[(MH) * 4 + m2][(NH) * 2 + n2] = __builtin_amdgcn_mfma_f32_16x16x32_bf16( \
            aF[m2][0], BF[n2][0], acc[(MH) * 4 + m2][(NH) * 2 + n2], 0, 0, 0); \
        acc[(MH) * 4 + m2][(NH) * 2 + n2] = __builtin_amdgcn_mfma_f32_16x16x32_bf16( \
            aF[m2][1], BF[n2][1], acc[(MH) * 4 + m2][(NH) * 2 + n2], 0, 0, 0); \
      } \
    } \
    __builtin_amdgcn_s_setprio(0); \
  } while (0)

#define BARMID do { \
    __builtin_amdgcn_s_barrier(); \
    asm volatile("s_waitcnt lgkmcnt(0)" ::: "memory"); \
    __builtin_amdgcn_sched_barrier(0); \
  } while (0)

template <int KIND>  // 0 shared-up, 1 routed-up, 2 shared-down splitK, 3 routed-down
__global__ __launch_bounds__(512, 2) void gemm8p(
    const unsigned short* __restrict__ A, const unsigned short* __restrict__ Ball,
    const int* __restrict__ cnt, const int* __restrict__ offs,
    const int* __restrict__ list, const float* __restrict__ cw,
    unsigned short* __restrict__ hout, float* __restrict__ fout,
    const int* __restrict__ table) {
    constexpr bool ROUTED = (KIND == 1 || KIND == 3);
    constexpr bool UP = (KIND <= 1);
    constexpr int K = (KIND <= 1) ? 2048 : 1024;
    constexpr int NT = K / 64;
    constexpr int ASTR = (KIND == 3) ? 1024 : 2048;
    constexpr int BSTR = (KIND == 3) ? 1024 : 2048;

    int bx, rb, e, M, obase;
    if constexpr (ROUTED) {
        int bid = blockIdx.x;
        int slot = bid >> 3;
        if (slot >= table[255]) return;
        bx = bid & 7;
        e = table[slot];
        rb = table[128 + slot];
        M = cnt[e];
        obase = offs[e];
    } else {
        bx = blockIdx.x; rb = blockIdx.y * 256; e = 0; M = T_TOK; obase = 0;
    }
    const int kb = (KIND == 2) ? blockIdx.z * 1024 : 0;
    const unsigned short* Bp = Ball +
        (KIND == 1 ? (size_t)e * 2048 * 2048 : KIND == 3 ? (size_t)e * 2048 * 1024 : 0);

    extern __shared__ char smem[];

    const int tid = threadIdx.x;
    const int lane = tid & 63, wid = tid >> 6;
    const int wm = wid >> 2, wn = wid & 3;
    const int fr = lane & 15, fq = lane >> 4;
    const int swz = (fr & 7) << 4;
    const int kA0 = (fq * 16) ^ swz;
    const int kA1 = (64 + fq * 16) ^ swz;

    int ldsA[2][2], ldsB[2][2];
    const unsigned short* gA[2][2];
    const unsigned short* gB[2][2];
#pragma unroll
    for (int u = 0; u < 2; ++u)
#pragma unroll
        for (int i = 0; i < 2; ++i) {
            int rowA = i * 128 + u * 64 + (tid >> 3);
            int kcA = (tid & 7) ^ (rowA & 7);
            ldsA[u][i] = i * 16384 + u * 8192 + tid * 16;
            int gr = rb + rowA;
            int cr = (gr < M) ? gr : (M - 1);
            size_t arow;
            if (KIND == 1)      arow = (size_t)list[e * T_TOK + cr];
            else if (KIND == 3) arow = (size_t)(obase + cr);
            else                arow = (size_t)gr;
            gA[u][i] = A + arow * ASTR + kb + kcA * 8;

            int s = (tid >> 8) + 2 * i;
            int rowB = s * 64 + u * 32 + ((tid >> 3) & 31);
            int kcB = (tid & 7) ^ (rowB & 7);
            ldsB[u][i] = s * 8192 + u * 4096 + (tid & 255) * 16;
            gB[u][i] = Bp + (size_t)(bx * 256 + rowB) * BSTR + kb + kcB * 8;
        }

    f32x4 acc[8][4];
#pragma unroll
    for (int m = 0; m < 8; ++m)
#pragma unroll
        for (int n = 0; n < 4; ++n) acc[m][n] = (f32x4)0.f;

    short8 aF[4][2], bF0[2][2], bF1[2][2];

    // prologue: B(0)->b0, B(1)->b1, A(0)->a0
    STBU(65536, 0, 0); STBU(65536, 0, 1);
    STBU(65536 + 32768, 1, 0); STBU(65536 + 32768, 1, 1);
    STA4(0, 0);
    asm volatile("s_waitcnt vmcnt(0)" ::: "memory");
    __builtin_amdgcn_s_barrier();

    int bB = 0, bB2 = 2;
    for (int t = 0; t < NT; ++t) {
        const int baseA = (t & 1) * 32768;
        const int baseAn = ((t + 1) & 1) * 32768;
        const int baseB = 65536 + bB * 32768;
        const int baseBn = 65536 + bB2 * 32768;
        const bool moreA = (t + 1 < NT);
        const bool moreB = (t + 2 < NT);
        // phase A
        RDA(baseA, 0); RDB(bF0, baseB, 0);
        if (moreA) STA4(baseAn, t + 1);
        BARMID;
        MM(0, 0, bF0);
        __builtin_amdgcn_s_barrier();
        // phase B
        RDB(bF1, baseB, 1);
        if (moreB) STBU(baseBn, t + 2, 0);
        BARMID;
        MM(0, 1, bF1);
        __builtin_amdgcn_s_barrier();
        // phase C
        RDA(baseA, 1);
        if (moreB) STBU(baseBn, t + 2, 1);
        BARMID;
        MM(1, 1, bF1);
        __builtin_amdgcn_s_barrier();
        // phase D
        MM(1, 0, bF0);
        if (moreB) { asm volatile("s_waitcnt vmcnt(4)" ::: "memory"); }
        else       { asm volatile("s_waitcnt vmcnt(0)" ::: "memory"); }
        __builtin_amdgcn_s_barrier();
        bB = (bB == 2) ? 0 : bB + 1;
        bB2 = (bB2 == 2) ? 0 : bB2 + 1;
    }

    // epilogue
    if constexpr (UP) {
        constexpr int LDO = (KIND == 1) ? NI : NSH;
#pragma unroll
        for (int mf = 0; mf < 8; ++mf)
#pragma unroll
            for (int q = 0; q < 4; ++q) {
                int gr = rb + wm * 128 + mf * 16 + fq * 4 + q;
                if (gr < M) {
                    float coef = 1.f;
                    if constexpr (KIND == 1) coef = cw[e * T_TOK + gr];
                    size_t orow = (size_t)(obase + gr) * LDO;
#pragma unroll
                    for (int nfp = 0; nfp < 2; ++nfp) {
                        float c1 = acc[mf][2 * nfp][q], c3 = acc[mf][2 * nfp + 1][q];
                        float h = c1 / (1.f + __expf(-c1)) * c3 * coef;
                        int ncol = (bx * 8 + wn * 2 + nfp) * 16 + fr;
                        hout[orow + ncol] = f2bf(h);
                    }
                }
            }
    } else {
#pragma unroll
        for (int mf = 0; mf < 8; ++mf)
#pragma unroll
            for (int q = 0; q < 4; ++q) {
                int gr = rb + wm * 128 + mf * 16 + fq * 4 + q;
                if (gr < M) {
                    int orow = (KIND == 3) ? list[e * T_TOK + gr] : gr;
#pragma unroll
                    for (int nf = 0; nf < 4; ++nf) {
                        int col = bx * 256 + wn * 64 + nf * 16 + fr;
                        atomicAdd(fout + (size_t)orow * DIMD + col, acc[mf][nf][q]);
                    }
                }
            }
    }
}

extern "C" void kernel_launch(void* const* d_in, const int* in_sizes, int n_in,
                              void* d_out, int out_size, void* d_ws, size_t ws_size,
                              hipStream_t stream) {
    const float* x   = (const float*)d_in[0];
    const float* gw  = (const float*)d_in[1];
    const float* w1  = (const float*)d_in[2];
    const float* w2  = (const float*)d_in[3];
    const float* w3  = (const float*)d_in[4];
    const float* ws1 = (const float*)d_in[5];
    const float* ws2 = (const float*)d_in[6];
    const float* ws3 = (const float*)d_in[7];
    float* out = (float*)d_out;

    char* p = (char*)d_ws;
    unsigned short* xb   = (unsigned short*)p; p += (size_t)T_TOK * DIMD * 2;
    unsigned short* hs   = (unsigned short*)p; p += (size_t)T_TOK * NSH * 2;
    unsigned short* hbuf = (unsigned short*)p; p += (size_t)T_TOK * TOPK * NI * 2;
    unsigned short* upT  = (unsigned short*)p; p += (size_t)NEXP * 2048 * DIMD * 2;
    unsigned short* w2T  = (unsigned short*)p; p += (size_t)NEXP * DIMD * NI * 2;
    unsigned short* upsT = (unsigned short*)p; p += (size_t)2 * NSH * DIMD * 2;
    unsigned short* ws2T = (unsigned short*)p; p += (size_t)DIMD * NSH * 2;
    float* gwT = (float*)p;                    p += (size_t)NEXP * DIMD * 4;
    float* cw = (float*)p;                     p += (size_t)NEXP * T_TOK * 4;
    int* list = (int*)p;                       p += (size_t)NEXP * T_TOK * 4;
    int* cnt = (int*)p;                        p += 256;
    int* offs = (int*)p;                       p += 256;
    int* table = (int*)p;                      p += 1024;
    if ((size_t)(p - (char*)d_ws) > ws_size) return;

    hipFuncSetAttribute((const void*)&gemm8p<0>, hipFuncAttributeMaxDynamicSharedMemorySize, 163840);
    hipFuncSetAttribute((const void*)&gemm8p<1>, hipFuncAttributeMaxDynamicSharedMemorySize, 163840);
    hipFuncSetAttribute((const void*)&gemm8p<2>, hipFuncAttributeMaxDynamicSharedMemorySize, 163840);
    hipFuncSetAttribute((const void*)&gemm8p<3>, hipFuncAttributeMaxDynamicSharedMemorySize, 163840);

    hipMemsetAsync(cnt, 0, 64, stream);
    hipMemsetAsync(out, 0, (size_t)out_size * 4, stream);
    gwt_kernel<<<(NEXP * DIMD) / 256, 256, 0, stream>>>(gw, gwT);
    gate_kernel<<<T_TOK / 4, 256, 0, stream>>>(x, gwT, cnt, list, cw);
    scan_kernel<<<1, 64, 0, stream>>>(cnt, offs, table);
    cvt_kernel<<<(T_TOK * DIMD / 8) / 256, 256, 0, stream>>>(x, xb);

    tq_kernel<1><<<dim3(NI / 32, DIMD / 32, NEXP), 256, 0, stream>>>(w1, upT, DIMD, NI, (size_t)2048 * DIMD);
    tq_kernel<2><<<dim3(NI / 32, DIMD / 32, NEXP), 256, 0, stream>>>(w3, upT, DIMD, NI, (size_t)2048 * DIMD);
    tq_kernel<1><<<dim3(NSH / 32, DIMD / 32, 1), 256, 0, stream>>>(ws1, upsT, DIMD, NSH, 0);
    tq_kernel<2><<<dim3(NSH / 32, DIMD / 32, 1), 256, 0, stream>>>(ws3, upsT, DIMD, NSH, 0);
    tq_kernel<0><<<dim3(DIMD / 32, NI / 32, NEXP), 256, 0, stream>>>(w2, w2T, NI, DIMD, (size_t)DIMD * NI);
    tq_kernel<0><<<dim3(DIMD / 32, NSH / 32, 1), 256, 0, stream>>>(ws2, ws2T, NSH, DIMD, 0);

    gemm8p<0><<<dim3(16, 16, 1), 512, 163840, stream>>>(
        xb, upsT, nullptr, nullptr, nullptr, nullptr, hs, nullptr, nullptr);
    gemm8p<2><<<dim3(8, 16, 2), 512, 163840, stream>>>(
        hs, ws2T, nullptr, nullptr, nullptr, nullptr, nullptr, out, nullptr);
    gemm8p<1><<<640, 512, 163840, stream>>>(
        xb, upT, cnt, offs, list, cw, hbuf, nullptr, table);
    gemm8p<3><<<640, 512, 163840, stream>>>(
        hbuf, w2T, cnt, offs, list, nullptr, nullptr, out, table);
}

// Round 7
// 726.831 us; speedup vs baseline: 1.2259x; 1.2259x over previous
//
#include <hip/hip_runtime.h>
#include <hip/hip_bf16.h>
#include <stdint.h>

#define T_TOK 4096
#define DIMD  2048
#define NEXP  16
#define TOPK  4
#define NI    1024
#define NSH   2048

typedef __attribute__((ext_vector_type(8))) short short8;
typedef __attribute__((ext_vector_type(4))) float f32x4;
typedef __attribute__((ext_vector_type(4))) unsigned short u16x4;

__device__ __forceinline__ unsigned short f2bf(float f) {
    union { float f; unsigned u; } v; v.f = f;
    return (unsigned short)((v.u + 0x7fffu + ((v.u >> 16) & 1u)) >> 16);
}

__device__ __forceinline__ void gload16(const void* g, void* l) {
    __builtin_amdgcn_global_load_lds(
        (const __attribute__((address_space(1))) void*)g,
        (__attribute__((address_space(3))) void*)l, 16, 0, 0);
}

// ---------------- gw transpose: [2048][16] -> [16][2048] fp32 ----------------
__global__ __launch_bounds__(256) void gwt_kernel(const float* __restrict__ gw,
                                                  float* __restrict__ gwT) {
    int i = blockIdx.x * 256 + threadIdx.x;   // 32768 elements
    int d = i >> 4, e = i & 15;
    gwT[e * DIMD + d] = gw[i];
}

// ---------------- gate: scores + top-4, NO global atomics ----------------
// 4 tokens/block (4 waves). LDS histogram -> per-block counts + per-token ranks.
__global__ __launch_bounds__(256) void gate_kernel(const float* __restrict__ x,
                                                   const float* __restrict__ gwT,
                                                   int* __restrict__ blk_cnt,
                                                   int* __restrict__ tk_er,
                                                   float* __restrict__ tk_wv) {
    __shared__ int h[16];
    const int blk = blockIdx.x;
    const int t = blk * 4 + (threadIdx.x >> 6);
    const int lane = threadIdx.x & 63;
    if (threadIdx.x < 16) h[threadIdx.x] = 0;
    __syncthreads();

    const f32x4* xr = (const f32x4*)(x + (size_t)t * DIMD);
    f32x4 xv[8];
#pragma unroll
    for (int i = 0; i < 8; ++i) xv[i] = xr[i * 64 + lane];

    float acc[NEXP];
#pragma unroll
    for (int e = 0; e < NEXP; ++e) {
        const f32x4* gr = (const f32x4*)(gwT + e * DIMD);
        float s = 0.f;
#pragma unroll
        for (int i = 0; i < 8; ++i) {
            f32x4 gv = gr[i * 64 + lane];
            s += xv[i][0] * gv[0] + xv[i][1] * gv[1] +
                 xv[i][2] * gv[2] + xv[i][3] * gv[3];
        }
        acc[e] = s;
    }
#pragma unroll
    for (int e = 0; e < NEXP; ++e) {
        float v = acc[e];
#pragma unroll
        for (int off = 32; off; off >>= 1) v += __shfl_xor(v, off, 64);
        acc[e] = v;
    }
    float m = acc[0];
#pragma unroll
    for (int e = 1; e < NEXP; ++e) m = fmaxf(m, acc[e]);
    float s = 0.f;
#pragma unroll
    for (int e = 0; e < NEXP; ++e) { acc[e] = expf(acc[e] - m); s += acc[e]; }
    float inv = 1.f / s;
#pragma unroll
    for (int e = 0; e < NEXP; ++e) acc[e] *= inv;

    float w4[TOPK]; int i4[TOPK];
#pragma unroll
    for (int k = 0; k < TOPK; ++k) {
        float bv = -1.f; int be = 0;
#pragma unroll
        for (int e = 0; e < NEXP; ++e)
            if (acc[e] > bv) { bv = acc[e]; be = e; }
        w4[k] = bv; i4[k] = be;
#pragma unroll
        for (int e = 0; e < NEXP; ++e)
            if (e == be) acc[e] = -1.f;
    }

    if (lane == 0) {
        int r4[TOPK];
#pragma unroll
        for (int k = 0; k < TOPK; ++k) r4[k] = atomicAdd(&h[i4[k]], 1);
#pragma unroll
        for (int k = 0; k < TOPK; ++k) {
            tk_er[t * 4 + k] = (i4[k] << 20) | r4[k];
            tk_wv[t * 4 + k] = w4[k];
        }
    }
    __syncthreads();
    if (threadIdx.x < 16) blk_cnt[blk * 16 + threadIdx.x] = h[threadIdx.x];
}

// ---------------- hierarchical scan: blk_off, cnt, offs, tile table ----------------
// 256 thr: thread = e*16+g; 16 groups x 64 blocks per expert.
__global__ __launch_bounds__(256) void scan_kernel(const int* __restrict__ blk_cnt,
                                                   int* __restrict__ blk_off,
                                                   int* __restrict__ cnt,
                                                   int* __restrict__ offs,
                                                   int* __restrict__ table) {
    __shared__ int gsum[16][17];
    __shared__ int gbase[16][17];
    __shared__ int csh[16];
    int tid = threadIdx.x;
    int e = tid >> 4, g = tid & 15;
    {
        int s = 0;
        for (int b = g * 64; b < g * 64 + 64; ++b) s += blk_cnt[b * 16 + e];
        gsum[e][g] = s;
    }
    __syncthreads();
    if (tid < 16) {
        int run = 0;
        for (int g2 = 0; g2 < 16; ++g2) { gbase[tid][g2] = run; run += gsum[tid][g2]; }
        csh[tid] = run;
        cnt[tid] = run;
    }
    __syncthreads();
    {
        int run = gbase[e][g];
        for (int b = g * 64; b < g * 64 + 64; ++b) {
            blk_off[b * 16 + e] = run;
            run += blk_cnt[b * 16 + e];
        }
    }
    if (tid == 0) {
        int o = 0;
        for (int e2 = 0; e2 < 16; ++e2) { offs[e2] = o; o += csh[e2]; }
        offs[NEXP] = o;
        int ns = 0;
        for (int e2 = 0; e2 < 16; ++e2)
            for (int rb = 0; rb < csh[e2]; rb += 256) {
                table[ns] = e2; table[128 + ns] = rb; ++ns;
            }
        table[255] = ns;
    }
}

// ---------------- fill compacted expert lists ----------------
__global__ __launch_bounds__(256) void fill_kernel(const int* __restrict__ tk_er,
                                                   const float* __restrict__ tk_wv,
                                                   const int* __restrict__ blk_off,
                                                   int* __restrict__ list,
                                                   float* __restrict__ cw) {
    int i = blockIdx.x * 256 + threadIdx.x;   // 16384 records
    int rec = tk_er[i];
    int e = rec >> 20, r = rec & 0xFFFFF;
    int t = i >> 2;
    int ro = blk_off[(t >> 2) * 16 + e] + r;
    list[e * T_TOK + ro] = t;
    cw[e * T_TOK + ro] = tk_wv[i];
}

// ---------------- x fp32 -> bf16 ----------------
__global__ __launch_bounds__(256) void cvt_kernel(const float* __restrict__ x,
                                                  unsigned short* __restrict__ xb) {
    int i = blockIdx.x * 256 + threadIdx.x;
    const f32x4* src = (const f32x4*)x;
    f32x4 a = src[i * 2 + 0];
    f32x4 b = src[i * 2 + 1];
    short8 o;
#pragma unroll
    for (int j = 0; j < 4; ++j) o[j] = (short)f2bf(a[j]);
#pragma unroll
    for (int j = 0; j < 4; ++j) o[4 + j] = (short)f2bf(b[j]);
    ((short8*)xb)[i] = o;
}

// ---------------- weight transpose + convert ----------------
template <int MODE>
__global__ __launch_bounds__(256) void tq_kernel(const float* __restrict__ src,
                                                 unsigned short* __restrict__ dst,
                                                 int K, int N, size_t dstStrideE) {
    int e = blockIdx.z;
    src += (size_t)e * K * N;
    dst += (size_t)e * dstStrideE;
    __shared__ unsigned short tile[32][36];
    int t = threadIdx.x;
    int k0 = blockIdx.y * 32, n0 = blockIdx.x * 32;
    {
        int row = t >> 3, c4 = (t & 7) * 4;
        f32x4 v = *(const f32x4*)(src + (size_t)(k0 + row) * N + n0 + c4);
#pragma unroll
        for (int j = 0; j < 4; ++j) tile[row][c4 + j] = f2bf(v[j]);
    }
    __syncthreads();
    {
        int nn = t >> 3, kc = (t & 7) * 4;
        int n = n0 + nn;
        int r = (MODE == 0) ? n : ((n >> 4) * 32 + (MODE == 2 ? 16 : 0) + (n & 15));
        u16x4 o;
#pragma unroll
        for (int j = 0; j < 4; ++j) o[j] = tile[kc + j][nn];
        *(u16x4*)(dst + (size_t)r * K + k0 + kc) = o;
    }
}

// ================= 256x256 GEMM, deep pipeline =================
// LDS 160KB: A double-buffer [0,32K),[32K,64K); B triple-buffer 64K+{0,1,2}*32K.

#define STA4(base, kt) do { \
    gload16(gA[0][0] + (kt) * 64, (void*)(smem + (base) + ldsA[0][0])); \
    gload16(gA[0][1] + (kt) * 64, (void*)(smem + (base) + ldsA[0][1])); \
    gload16(gA[1][0] + (kt) * 64, (void*)(smem + (base) + ldsA[1][0])); \
    gload16(gA[1][1] + (kt) * 64, (void*)(smem + (base) + ldsA[1][1])); \
  } while (0)
#define STBU(base, kt, u) do { \
    gload16(gB[u][0] + (kt) * 64, (void*)(smem + (base) + ldsB[u][0])); \
    gload16(gB[u][1] + (kt) * 64, (void*)(smem + (base) + ldsB[u][1])); \
  } while (0)

#define RDA(base, MH) do { \
    _Pragma("unroll") \
    for (int m2 = 0; m2 < 4; ++m2) { \
      const char* bp = smem + (base) + (wm * 128 + (MH) * 64 + m2 * 16 + fr) * 128; \
      aF[m2][0] = *(const short8*)(bp + kA0); \
      aF[m2][1] = *(const short8*)(bp + kA1); \
    } } while (0)
#define RDB(dst, base, NH) do { \
    _Pragma("unroll") \
    for (int n2 = 0; n2 < 2; ++n2) { \
      const char* bp = smem + (base) + (wn * 64 + (NH) * 32 + n2 * 16 + fr) * 128; \
      dst[n2][0] = *(const short8*)(bp + kA0); \
      dst[n2][1] = *(const short8*)(bp + kA1); \
    } } while (0)

#define MM(MH, NH, BF) do { \
    __builtin_amdgcn_s_setprio(1); \
    _Pragma("unroll") \
    for (int m2 = 0; m2 < 4; ++m2) { \
      _Pragma("unroll") \
      for (int n2 = 0; n2 < 2; ++n2) { \
        acc[(MH) * 4 + m2][(NH) * 2 + n2] = __builtin_amdgcn_mfma_f32_16x16x32_bf16( \
            aF[m2][0], BF[n2][0], acc[(MH) * 4 + m2][(NH) * 2 + n2], 0, 0, 0); \
        acc[(MH) * 4 + m2][(NH) * 2 + n2] = __builtin_amdgcn_mfma_f32_16x16x32_bf16( \
            aF[m2][1], BF[n2][1], acc[(MH) * 4 + m2][(NH) * 2 + n2], 0, 0, 0); \
      } \
    } \
    __builtin_amdgcn_s_setprio(0); \
  } while (0)

#define BARMID do { \
    __builtin_amdgcn_s_barrier(); \
    asm volatile("s_waitcnt lgkmcnt(0)" ::: "memory"); \
    __builtin_amdgcn_sched_barrier(0); \
  } while (0)

template <int KIND>  // 0 shared-up, 1 routed-up, 2 shared-down splitK, 3 routed-down
__global__ __launch_bounds__(512, 2) void gemm8p(
    const unsigned short* __restrict__ A, const unsigned short* __restrict__ Ball,
    const int* __restrict__ cnt, const int* __restrict__ offs,
    const int* __restrict__ list, const float* __restrict__ cw,
    unsigned short* __restrict__ hout, float* __restrict__ fout,
    const int* __restrict__ table) {
    constexpr bool ROUTED = (KIND == 1 || KIND == 3);
    constexpr bool UP = (KIND <= 1);
    constexpr int K = (KIND <= 1) ? 2048 : 1024;
    constexpr int NT = K / 64;
    constexpr int ASTR = (KIND == 3) ? 1024 : 2048;
    constexpr int BSTR = (KIND == 3) ? 1024 : 2048;

    int bx, rb, e, M, obase;
    if constexpr (ROUTED) {
        int bid = blockIdx.x;
        int slot = bid >> 3;
        if (slot >= table[255]) return;
        bx = bid & 7;
        e = table[slot];
        rb = table[128 + slot];
        M = cnt[e];
        obase = offs[e];
    } else {
        bx = blockIdx.x; rb = blockIdx.y * 256; e = 0; M = T_TOK; obase = 0;
    }
    const int kb = (KIND == 2) ? blockIdx.z * 1024 : 0;
    const unsigned short* Bp = Ball +
        (KIND == 1 ? (size_t)e * 2048 * 2048 : KIND == 3 ? (size_t)e * 2048 * 1024 : 0);

    extern __shared__ char smem[];

    const int tid = threadIdx.x;
    const int lane = tid & 63, wid = tid >> 6;
    const int wm = wid >> 2, wn = wid & 3;
    const int fr = lane & 15, fq = lane >> 4;
    const int swz = (fr & 7) << 4;
    const int kA0 = (fq * 16) ^ swz;
    const int kA1 = (64 + fq * 16) ^ swz;

    int ldsA[2][2], ldsB[2][2];
    const unsigned short* gA[2][2];
    const unsigned short* gB[2][2];
#pragma unroll
    for (int u = 0; u < 2; ++u)
#pragma unroll
        for (int i = 0; i < 2; ++i) {
            int rowA = i * 128 + u * 64 + (tid >> 3);
            int kcA = (tid & 7) ^ (rowA & 7);
            ldsA[u][i] = i * 16384 + u * 8192 + tid * 16;
            int gr = rb + rowA;
            int cr = (gr < M) ? gr : (M - 1);
            size_t arow;
            if (KIND == 1)      arow = (size_t)list[e * T_TOK + cr];
            else if (KIND == 3) arow = (size_t)(obase + cr);
            else                arow = (size_t)gr;
            gA[u][i] = A + arow * ASTR + kb + kcA * 8;

            int s = (tid >> 8) + 2 * i;
            int rowB = s * 64 + u * 32 + ((tid >> 3) & 31);
            int kcB = (tid & 7) ^ (rowB & 7);
            ldsB[u][i] = s * 8192 + u * 4096 + (tid & 255) * 16;
            gB[u][i] = Bp + (size_t)(bx * 256 + rowB) * BSTR + kb + kcB * 8;
        }

    f32x4 acc[8][4];
#pragma unroll
    for (int m = 0; m < 8; ++m)
#pragma unroll
        for (int n = 0; n < 4; ++n) acc[m][n] = (f32x4)0.f;

    short8 aF[4][2], bF0[2][2], bF1[2][2];

    // prologue: B(0)->b0, B(1)->b1, A(0)->a0
    STBU(65536, 0, 0); STBU(65536, 0, 1);
    STBU(65536 + 32768, 1, 0); STBU(65536 + 32768, 1, 1);
    STA4(0, 0);
    asm volatile("s_waitcnt vmcnt(0)" ::: "memory");
    __builtin_amdgcn_s_barrier();

    int bB = 0, bB2 = 2;
    for (int t = 0; t < NT; ++t) {
        const int baseA = (t & 1) * 32768;
        const int baseAn = ((t + 1) & 1) * 32768;
        const int baseB = 65536 + bB * 32768;
        const int baseBn = 65536 + bB2 * 32768;
        const bool moreA = (t + 1 < NT);
        const bool moreB = (t + 2 < NT);
        // phase A
        RDA(baseA, 0); RDB(bF0, baseB, 0);
        if (moreA) STA4(baseAn, t + 1);
        BARMID;
        MM(0, 0, bF0);
        __builtin_amdgcn_s_barrier();
        // phase B
        RDB(bF1, baseB, 1);
        if (moreB) STBU(baseBn, t + 2, 0);
        BARMID;
        MM(0, 1, bF1);
        __builtin_amdgcn_s_barrier();
        // phase C
        RDA(baseA, 1);
        if (moreB) STBU(baseBn, t + 2, 1);
        BARMID;
        MM(1, 1, bF1);
        __builtin_amdgcn_s_barrier();
        // phase D
        MM(1, 0, bF0);
        if (moreB) { asm volatile("s_waitcnt vmcnt(4)" ::: "memory"); }
        else       { asm volatile("s_waitcnt vmcnt(0)" ::: "memory"); }
        __builtin_amdgcn_s_barrier();
        bB = (bB == 2) ? 0 : bB + 1;
        bB2 = (bB2 == 2) ? 0 : bB2 + 1;
    }

    // epilogue
    if constexpr (UP) {
        constexpr int LDO = (KIND == 1) ? NI : NSH;
#pragma unroll
        for (int mf = 0; mf < 8; ++mf)
#pragma unroll
            for (int q = 0; q < 4; ++q) {
                int gr = rb + wm * 128 + mf * 16 + fq * 4 + q;
                if (gr < M) {
                    float coef = 1.f;
                    if constexpr (KIND == 1) coef = cw[e * T_TOK + gr];
                    size_t orow = (size_t)(obase + gr) * LDO;
#pragma unroll
                    for (int nfp = 0; nfp < 2; ++nfp) {
                        float c1 = acc[mf][2 * nfp][q], c3 = acc[mf][2 * nfp + 1][q];
                        float h = c1 / (1.f + __expf(-c1)) * c3 * coef;
                        int ncol = (bx * 8 + wn * 2 + nfp) * 16 + fr;
                        hout[orow + ncol] = f2bf(h);
                    }
                }
            }
    } else {
#pragma unroll
        for (int mf = 0; mf < 8; ++mf)
#pragma unroll
            for (int q = 0; q < 4; ++q) {
                int gr = rb + wm * 128 + mf * 16 + fq * 4 + q;
                if (gr < M) {
                    int orow = (KIND == 3) ? list[e * T_TOK + gr] : gr;
#pragma unroll
                    for (int nf = 0; nf < 4; ++nf) {
                        int col = bx * 256 + wn * 64 + nf * 16 + fr;
                        atomicAdd(fout + (size_t)orow * DIMD + col, acc[mf][nf][q]);
                    }
                }
            }
    }
}

extern "C" void kernel_launch(void* const* d_in, const int* in_sizes, int n_in,
                              void* d_out, int out_size, void* d_ws, size_t ws_size,
                              hipStream_t stream) {
    const float* x   = (const float*)d_in[0];
    const float* gw  = (const float*)d_in[1];
    const float* w1  = (const float*)d_in[2];
    const float* w2  = (const float*)d_in[3];
    const float* w3  = (const float*)d_in[4];
    const float* ws1 = (const float*)d_in[5];
    const float* ws2 = (const float*)d_in[6];
    const float* ws3 = (const float*)d_in[7];
    float* out = (float*)d_out;

    char* p = (char*)d_ws;
    unsigned short* xb   = (unsigned short*)p; p += (size_t)T_TOK * DIMD * 2;
    unsigned short* hs   = (unsigned short*)p; p += (size_t)T_TOK * NSH * 2;
    unsigned short* hbuf = (unsigned short*)p; p += (size_t)T_TOK * TOPK * NI * 2;
    unsigned short* upT  = (unsigned short*)p; p += (size_t)NEXP * 2048 * DIMD * 2;
    unsigned short* w2T  = (unsigned short*)p; p += (size_t)NEXP * DIMD * NI * 2;
    unsigned short* upsT = (unsigned short*)p; p += (size_t)2 * NSH * DIMD * 2;
    unsigned short* ws2T = (unsigned short*)p; p += (size_t)DIMD * NSH * 2;
    float* gwT = (float*)p;                    p += (size_t)NEXP * DIMD * 4;
    float* cw = (float*)p;                     p += (size_t)NEXP * T_TOK * 4;
    int* list = (int*)p;                       p += (size_t)NEXP * T_TOK * 4;
    int* tk_er = (int*)p;                      p += (size_t)T_TOK * TOPK * 4;
    float* tk_wv = (float*)p;                  p += (size_t)T_TOK * TOPK * 4;
    int* blk_cnt = (int*)p;                    p += (size_t)1024 * 16 * 4;
    int* blk_off = (int*)p;                    p += (size_t)1024 * 16 * 4;
    int* cnt = (int*)p;                        p += 256;
    int* offs = (int*)p;                       p += 256;
    int* table = (int*)p;                      p += 1024;
    if ((size_t)(p - (char*)d_ws) > ws_size) return;

    hipFuncSetAttribute((const void*)&gemm8p<0>, hipFuncAttributeMaxDynamicSharedMemorySize, 163840);
    hipFuncSetAttribute((const void*)&gemm8p<1>, hipFuncAttributeMaxDynamicSharedMemorySize, 163840);
    hipFuncSetAttribute((const void*)&gemm8p<2>, hipFuncAttributeMaxDynamicSharedMemorySize, 163840);
    hipFuncSetAttribute((const void*)&gemm8p<3>, hipFuncAttributeMaxDynamicSharedMemorySize, 163840);

    hipMemsetAsync(out, 0, (size_t)out_size * 4, stream);
    gwt_kernel<<<(NEXP * DIMD) / 256, 256, 0, stream>>>(gw, gwT);
    gate_kernel<<<T_TOK / 4, 256, 0, stream>>>(x, gwT, blk_cnt, tk_er, tk_wv);
    scan_kernel<<<1, 256, 0, stream>>>(blk_cnt, blk_off, cnt, offs, table);
    fill_kernel<<<T_TOK * TOPK / 256, 256, 0, stream>>>(tk_er, tk_wv, blk_off, list, cw);
    cvt_kernel<<<(T_TOK * DIMD / 8) / 256, 256, 0, stream>>>(x, xb);

    tq_kernel<1><<<dim3(NI / 32, DIMD / 32, NEXP), 256, 0, stream>>>(w1, upT, DIMD, NI, (size_t)2048 * DIMD);
    tq_kernel<2><<<dim3(NI / 32, DIMD / 32, NEXP), 256, 0, stream>>>(w3, upT, DIMD, NI, (size_t)2048 * DIMD);
    tq_kernel<1><<<dim3(NSH / 32, DIMD / 32, 1), 256, 0, stream>>>(ws1, upsT, DIMD, NSH, 0);
    tq_kernel<2><<<dim3(NSH / 32, DIMD / 32, 1), 256, 0, stream>>>(ws3, upsT, DIMD, NSH, 0);
    tq_kernel<0><<<dim3(DIMD / 32, NI / 32, NEXP), 256, 0, stream>>>(w2, w2T, NI, DIMD, (size_t)DIMD * NI);
    tq_kernel<0><<<dim3(DIMD / 32, NSH / 32, 1), 256, 0, stream>>>(ws2, ws2T, NSH, DIMD, 0);

    gemm8p<0><<<dim3(16, 16, 1), 512, 163840, stream>>>(
        xb, upsT, nullptr, nullptr, nullptr, nullptr, hs, nullptr, nullptr);
    gemm8p<2><<<dim3(8, 16, 2), 512, 163840, stream>>>(
        hs, ws2T, nullptr, nullptr, nullptr, nullptr, nullptr, out, nullptr);
    gemm8p<1><<<640, 512, 163840, stream>>>(
        xb, upT, cnt, offs, list, cw, hbuf, nullptr, table);
    gemm8p<3><<<640, 512, 163840, stream>>>(
        hbuf, w2T, cnt, offs, list, nullptr, nullptr, out, table);
}

// Round 8
// 715.432 us; speedup vs baseline: 1.2455x; 1.0159x over previous
//
#include <hip/hip_runtime.h>
#include <hip/hip_bf16.h>
#include <stdint.h>

#define T_TOK 4096
#define DIMD  2048
#define NEXP  16
#define TOPK  4
#define NI    1024
#define NSH   2048

typedef __attribute__((ext_vector_type(8))) short short8;
typedef __attribute__((ext_vector_type(4))) float f32x4;
typedef __attribute__((ext_vector_type(4))) unsigned short u16x4;

__device__ __forceinline__ unsigned short f2bf(float f) {
    union { float f; unsigned u; } v; v.f = f;
    return (unsigned short)((v.u + 0x7fffu + ((v.u >> 16) & 1u)) >> 16);
}

__device__ __forceinline__ void gload16(const void* g, void* l) {
    __builtin_amdgcn_global_load_lds(
        (const __attribute__((address_space(1))) void*)g,
        (__attribute__((address_space(3))) void*)l, 16, 0, 0);
}

// ---------------- gw transpose: [2048][16] -> [16][2048] fp32 ----------------
__global__ __launch_bounds__(256) void gwt_kernel(const float* __restrict__ gw,
                                                  float* __restrict__ gwT) {
    int i = blockIdx.x * 256 + threadIdx.x;   // 32768 elements
    int d = i >> 4, e = i & 15;
    gwT[e * DIMD + d] = gw[i];
}

// ---------------- gate: scores + top-4, NO global atomics ----------------
__global__ __launch_bounds__(256) void gate_kernel(const float* __restrict__ x,
                                                   const float* __restrict__ gwT,
                                                   int* __restrict__ blk_cnt,
                                                   int* __restrict__ tk_er,
                                                   float* __restrict__ tk_wv) {
    __shared__ int h[16];
    const int blk = blockIdx.x;
    const int t = blk * 4 + (threadIdx.x >> 6);
    const int lane = threadIdx.x & 63;
    if (threadIdx.x < 16) h[threadIdx.x] = 0;
    __syncthreads();

    const f32x4* xr = (const f32x4*)(x + (size_t)t * DIMD);
    f32x4 xv[8];
#pragma unroll
    for (int i = 0; i < 8; ++i) xv[i] = xr[i * 64 + lane];

    float acc[NEXP];
#pragma unroll
    for (int e = 0; e < NEXP; ++e) {
        const f32x4* gr = (const f32x4*)(gwT + e * DIMD);
        float s = 0.f;
#pragma unroll
        for (int i = 0; i < 8; ++i) {
            f32x4 gv = gr[i * 64 + lane];
            s += xv[i][0] * gv[0] + xv[i][1] * gv[1] +
                 xv[i][2] * gv[2] + xv[i][3] * gv[3];
        }
        acc[e] = s;
    }
#pragma unroll
    for (int e = 0; e < NEXP; ++e) {
        float v = acc[e];
#pragma unroll
        for (int off = 32; off; off >>= 1) v += __shfl_xor(v, off, 64);
        acc[e] = v;
    }
    float m = acc[0];
#pragma unroll
    for (int e = 1; e < NEXP; ++e) m = fmaxf(m, acc[e]);
    float s = 0.f;
#pragma unroll
    for (int e = 0; e < NEXP; ++e) { acc[e] = expf(acc[e] - m); s += acc[e]; }
    float inv = 1.f / s;
#pragma unroll
    for (int e = 0; e < NEXP; ++e) acc[e] *= inv;

    float w4[TOPK]; int i4[TOPK];
#pragma unroll
    for (int k = 0; k < TOPK; ++k) {
        float bv = -1.f; int be = 0;
#pragma unroll
        for (int e = 0; e < NEXP; ++e)
            if (acc[e] > bv) { bv = acc[e]; be = e; }
        w4[k] = bv; i4[k] = be;
#pragma unroll
        for (int e = 0; e < NEXP; ++e)
            if (e == be) acc[e] = -1.f;
    }

    if (lane == 0) {
        int r4[TOPK];
#pragma unroll
        for (int k = 0; k < TOPK; ++k) r4[k] = atomicAdd(&h[i4[k]], 1);
#pragma unroll
        for (int k = 0; k < TOPK; ++k) {
            tk_er[t * 4 + k] = (i4[k] << 20) | r4[k];
            tk_wv[t * 4 + k] = w4[k];
        }
    }
    __syncthreads();
    if (threadIdx.x < 16) blk_cnt[blk * 16 + threadIdx.x] = h[threadIdx.x];
}

// ---------------- hierarchical scan ----------------
__global__ __launch_bounds__(256) void scan_kernel(const int* __restrict__ blk_cnt,
                                                   int* __restrict__ blk_off,
                                                   int* __restrict__ cnt,
                                                   int* __restrict__ offs,
                                                   int* __restrict__ table) {
    __shared__ int gsum[16][17];
    __shared__ int gbase[16][17];
    __shared__ int csh[16];
    int tid = threadIdx.x;
    int e = tid >> 4, g = tid & 15;
    {
        int s = 0;
        for (int b = g * 64; b < g * 64 + 64; ++b) s += blk_cnt[b * 16 + e];
        gsum[e][g] = s;
    }
    __syncthreads();
    if (tid < 16) {
        int run = 0;
        for (int g2 = 0; g2 < 16; ++g2) { gbase[tid][g2] = run; run += gsum[tid][g2]; }
        csh[tid] = run;
        cnt[tid] = run;
    }
    __syncthreads();
    {
        int run = gbase[e][g];
        for (int b = g * 64; b < g * 64 + 64; ++b) {
            blk_off[b * 16 + e] = run;
            run += blk_cnt[b * 16 + e];
        }
    }
    if (tid == 0) {
        int o = 0;
        for (int e2 = 0; e2 < 16; ++e2) { offs[e2] = o; o += csh[e2]; }
        offs[NEXP] = o;
        int ns = 0;
        for (int e2 = 0; e2 < 16; ++e2)
            for (int rb = 0; rb < csh[e2]; rb += 256) {
                table[ns] = e2; table[128 + ns] = rb; ++ns;
            }
        table[255] = ns;
    }
}

// ---------------- fill compacted expert lists ----------------
__global__ __launch_bounds__(256) void fill_kernel(const int* __restrict__ tk_er,
                                                   const float* __restrict__ tk_wv,
                                                   const int* __restrict__ blk_off,
                                                   int* __restrict__ list,
                                                   float* __restrict__ cw) {
    int i = blockIdx.x * 256 + threadIdx.x;   // 16384 records
    int rec = tk_er[i];
    int e = rec >> 20, r = rec & 0xFFFFF;
    int t = i >> 2;
    int ro = blk_off[(t >> 2) * 16 + e] + r;
    list[e * T_TOK + ro] = t;
    cw[e * T_TOK + ro] = tk_wv[i];
}

// ---------------- x fp32 -> bf16 ----------------
__global__ __launch_bounds__(256) void cvt_kernel(const float* __restrict__ x,
                                                  unsigned short* __restrict__ xb) {
    int i = blockIdx.x * 256 + threadIdx.x;
    const f32x4* src = (const f32x4*)x;
    f32x4 a = src[i * 2 + 0];
    f32x4 b = src[i * 2 + 1];
    short8 o;
#pragma unroll
    for (int j = 0; j < 4; ++j) o[j] = (short)f2bf(a[j]);
#pragma unroll
    for (int j = 0; j < 4; ++j) o[4 + j] = (short)f2bf(b[j]);
    ((short8*)xb)[i] = o;
}

// ---------------- weight transpose + convert ----------------
template <int MODE>
__global__ __launch_bounds__(256) void tq_kernel(const float* __restrict__ src,
                                                 unsigned short* __restrict__ dst,
                                                 int K, int N, size_t dstStrideE) {
    int e = blockIdx.z;
    src += (size_t)e * K * N;
    dst += (size_t)e * dstStrideE;
    __shared__ unsigned short tile[32][36];
    int t = threadIdx.x;
    int k0 = blockIdx.y * 32, n0 = blockIdx.x * 32;
    {
        int row = t >> 3, c4 = (t & 7) * 4;
        f32x4 v = *(const f32x4*)(src + (size_t)(k0 + row) * N + n0 + c4);
#pragma unroll
        for (int j = 0; j < 4; ++j) tile[row][c4 + j] = f2bf(v[j]);
    }
    __syncthreads();
    {
        int nn = t >> 3, kc = (t & 7) * 4;
        int n = n0 + nn;
        int r = (MODE == 0) ? n : ((n >> 4) * 32 + (MODE == 2 ? 16 : 0) + (n & 15));
        u16x4 o;
#pragma unroll
        for (int j = 0; j < 4; ++j) o[j] = tile[kc + j][nn];
        *(u16x4*)(dst + (size_t)r * K + k0 + kc) = o;
    }
}

// ================= 256x256 GEMM, deep pipeline, 1 barrier/K-tile =================
// LDS 160KB: A dbuf [0,32K),[32K,64K); B 3buf 64K+{0,1,2}*32K.
// Tile t body: read frags + MFMA (compiler-interleaved, no intra barriers),
// stage A(t+1) + B(t+2); end: vmcnt(4) [B(t+2) outstanding] + barrier.

#define STA4(base, kt) do { \
    gload16(gA[0][0] + (kt) * 64, (void*)(smem + (base) + ldsA[0][0])); \
    gload16(gA[0][1] + (kt) * 64, (void*)(smem + (base) + ldsA[0][1])); \
    gload16(gA[1][0] + (kt) * 64, (void*)(smem + (base) + ldsA[1][0])); \
    gload16(gA[1][1] + (kt) * 64, (void*)(smem + (base) + ldsA[1][1])); \
  } while (0)
#define STBU(base, kt, u) do { \
    gload16(gB[u][0] + (kt) * 64, (void*)(smem + (base) + ldsB[u][0])); \
    gload16(gB[u][1] + (kt) * 64, (void*)(smem + (base) + ldsB[u][1])); \
  } while (0)

#define RDA(base, MH) do { \
    _Pragma("unroll") \
    for (int m2 = 0; m2 < 4; ++m2) { \
      const char* bp = smem + (base) + (wm * 128 + (MH) * 64 + m2 * 16 + fr) * 128; \
      aF[m2][0] = *(const short8*)(bp + kA0); \
      aF[m2][1] = *(const short8*)(bp + kA1); \
    } } while (0)
#define RDB(dst, base, NH) do { \
    _Pragma("unroll") \
    for (int n2 = 0; n2 < 2; ++n2) { \
      const char* bp = smem + (base) + (wn * 64 + (NH) * 32 + n2 * 16 + fr) * 128; \
      dst[n2][0] = *(const short8*)(bp + kA0); \
      dst[n2][1] = *(const short8*)(bp + kA1); \
    } } while (0)

#define MM(MH, NH, BF) do { \
    __builtin_amdgcn_s_setprio(1); \
    _Pragma("unroll") \
    for (int m2 = 0; m2 < 4; ++m2) { \
      _Pragma("unroll") \
      for (int n2 = 0; n2 < 2; ++n2) { \
        acc[(MH) * 4 + m2][(NH) * 2 + n2] = __builtin_amdgcn_mfma_f32_16x16x32_bf16( \
            aF[m2][0], BF[n2][0], acc[(MH) * 4 + m2][(NH) * 2 + n2], 0, 0, 0); \
        acc[(MH) * 4 + m2][(NH) * 2 + n2] = __builtin_amdgcn_mfma_f32_16x16x32_bf16( \
            aF[m2][1], BF[n2][1], acc[(MH) * 4 + m2][(NH) * 2 + n2], 0, 0, 0); \
      } \
    } \
    __builtin_amdgcn_s_setprio(0); \
  } while (0)

template <int KIND>  // 0 shared-up, 1 routed-up, 2 shared-down splitK, 3 routed-down
__global__ __launch_bounds__(512, 2) void gemm8p(
    const unsigned short* __restrict__ A, const unsigned short* __restrict__ Ball,
    const int* __restrict__ cnt, const int* __restrict__ offs,
    const int* __restrict__ list, const float* __restrict__ cw,
    unsigned short* __restrict__ hout, float* __restrict__ fout,
    const int* __restrict__ table) {
    constexpr bool ROUTED = (KIND == 1 || KIND == 3);
    constexpr bool UP = (KIND <= 1);
    constexpr int K = (KIND <= 1) ? 2048 : 1024;
    constexpr int NT = K / 64;
    constexpr int ASTR = (KIND == 3) ? 1024 : 2048;
    constexpr int BSTR = (KIND == 3) ? 1024 : 2048;

    int bx, rb, e, M, obase;
    if constexpr (ROUTED) {
        int bid = blockIdx.x;
        int slot = bid >> 3;
        if (slot >= table[255]) return;
        bx = bid & 7;
        e = table[slot];
        rb = table[128 + slot];
        M = cnt[e];
        obase = offs[e];
    } else {
        bx = blockIdx.x; rb = blockIdx.y * 256; e = 0; M = T_TOK; obase = 0;
    }
    const int kb = (KIND == 2) ? blockIdx.z * 1024 : 0;
    const unsigned short* Bp = Ball +
        (KIND == 1 ? (size_t)e * 2048 * 2048 : KIND == 3 ? (size_t)e * 2048 * 1024 : 0);

    extern __shared__ char smem[];

    const int tid = threadIdx.x;
    const int lane = tid & 63, wid = tid >> 6;
    const int wm = wid >> 2, wn = wid & 3;
    const int fr = lane & 15, fq = lane >> 4;
    const int swz = (fr & 7) << 4;
    const int kA0 = (fq * 16) ^ swz;
    const int kA1 = (64 + fq * 16) ^ swz;

    int ldsA[2][2], ldsB[2][2];
    const unsigned short* gA[2][2];
    const unsigned short* gB[2][2];
#pragma unroll
    for (int u = 0; u < 2; ++u)
#pragma unroll
        for (int i = 0; i < 2; ++i) {
            int rowA = i * 128 + u * 64 + (tid >> 3);
            int kcA = (tid & 7) ^ (rowA & 7);
            ldsA[u][i] = i * 16384 + u * 8192 + tid * 16;
            int gr = rb + rowA;
            int cr = (gr < M) ? gr : (M - 1);
            size_t arow;
            if (KIND == 1)      arow = (size_t)list[e * T_TOK + cr];
            else if (KIND == 3) arow = (size_t)(obase + cr);
            else                arow = (size_t)gr;
            gA[u][i] = A + arow * ASTR + kb + kcA * 8;

            int s = (tid >> 8) + 2 * i;
            int rowB = s * 64 + u * 32 + ((tid >> 3) & 31);
            int kcB = (tid & 7) ^ (rowB & 7);
            ldsB[u][i] = s * 8192 + u * 4096 + (tid & 255) * 16;
            gB[u][i] = Bp + (size_t)(bx * 256 + rowB) * BSTR + kb + kcB * 8;
        }

    f32x4 acc[8][4];
#pragma unroll
    for (int m = 0; m < 8; ++m)
#pragma unroll
        for (int n = 0; n < 4; ++n) acc[m][n] = (f32x4)0.f;

    short8 aF[4][2], bF0[2][2], bF1[2][2];

    // prologue: B(0)->slot0, B(1)->slot1, A(0)->a0
    STBU(65536, 0, 0); STBU(65536, 0, 1);
    STBU(65536 + 32768, 1, 0); STBU(65536 + 32768, 1, 1);
    STA4(0, 0);
    asm volatile("s_waitcnt vmcnt(0)" ::: "memory");
    __builtin_amdgcn_s_barrier();

    int bB = 0, bB2 = 2;
    for (int t = 0; t < NT; ++t) {
        const int baseA = (t & 1) * 32768;
        const int baseAn = ((t + 1) & 1) * 32768;
        const int baseB = 65536 + bB * 32768;
        const int baseBn = 65536 + bB2 * 32768;
        const bool moreA = (t + 1 < NT);
        const bool moreB = (t + 2 < NT);

        // issue A stage first, then B stage (vmcnt(4) relies on this order)
        RDA(baseA, 0); RDB(bF0, baseB, 0);
        if (moreA) STA4(baseAn, t + 1);
        if (moreB) { STBU(baseBn, t + 2, 0); STBU(baseBn, t + 2, 1); }
        MM(0, 0, bF0);
        RDB(bF1, baseB, 1);
        MM(0, 1, bF1);
        RDA(baseA, 1);
        MM(1, 1, bF1);
        MM(1, 0, bF0);
        if (moreB) { asm volatile("s_waitcnt vmcnt(4)" ::: "memory"); }
        else       { asm volatile("s_waitcnt vmcnt(0)" ::: "memory"); }
        __builtin_amdgcn_s_barrier();
        bB = (bB == 2) ? 0 : bB + 1;
        bB2 = (bB2 == 2) ? 0 : bB2 + 1;
    }

    // epilogue
    if constexpr (UP) {
        constexpr int LDO = (KIND == 1) ? NI : NSH;
#pragma unroll
        for (int mf = 0; mf < 8; ++mf)
#pragma unroll
            for (int q = 0; q < 4; ++q) {
                int gr = rb + wm * 128 + mf * 16 + fq * 4 + q;
                if (gr < M) {
                    float coef = 1.f;
                    if constexpr (KIND == 1) coef = cw[e * T_TOK + gr];
                    size_t orow = (size_t)(obase + gr) * LDO;
#pragma unroll
                    for (int nfp = 0; nfp < 2; ++nfp) {
                        float c1 = acc[mf][2 * nfp][q], c3 = acc[mf][2 * nfp + 1][q];
                        float h = c1 / (1.f + __expf(-c1)) * c3 * coef;
                        int ncol = (bx * 8 + wn * 2 + nfp) * 16 + fr;
                        hout[orow + ncol] = f2bf(h);
                    }
                }
            }
    } else {
#pragma unroll
        for (int mf = 0; mf < 8; ++mf)
#pragma unroll
            for (int q = 0; q < 4; ++q) {
                int gr = rb + wm * 128 + mf * 16 + fq * 4 + q;
                if (gr < M) {
                    int orow = (KIND == 3) ? list[e * T_TOK + gr] : gr;
#pragma unroll
                    for (int nf = 0; nf < 4; ++nf) {
                        int col = bx * 256 + wn * 64 + nf * 16 + fr;
                        atomicAdd(fout + (size_t)orow * DIMD + col, acc[mf][nf][q]);
                    }
                }
            }
    }
}

extern "C" void kernel_launch(void* const* d_in, const int* in_sizes, int n_in,
                              void* d_out, int out_size, void* d_ws, size_t ws_size,
                              hipStream_t stream) {
    const float* x   = (const float*)d_in[0];
    const float* gw  = (const float*)d_in[1];
    const float* w1  = (const float*)d_in[2];
    const float* w2  = (const float*)d_in[3];
    const float* w3  = (const float*)d_in[4];
    const float* ws1 = (const float*)d_in[5];
    const float* ws2 = (const float*)d_in[6];
    const float* ws3 = (const float*)d_in[7];
    float* out = (float*)d_out;

    char* p = (char*)d_ws;
    unsigned short* xb   = (unsigned short*)p; p += (size_t)T_TOK * DIMD * 2;
    unsigned short* hs   = (unsigned short*)p; p += (size_t)T_TOK * NSH * 2;
    unsigned short* hbuf = (unsigned short*)p; p += (size_t)T_TOK * TOPK * NI * 2;
    unsigned short* upT  = (unsigned short*)p; p += (size_t)NEXP * 2048 * DIMD * 2;
    unsigned short* w2T  = (unsigned short*)p; p += (size_t)NEXP * DIMD * NI * 2;
    unsigned short* upsT = (unsigned short*)p; p += (size_t)2 * NSH * DIMD * 2;
    unsigned short* ws2T = (unsigned short*)p; p += (size_t)DIMD * NSH * 2;
    float* gwT = (float*)p;                    p += (size_t)NEXP * DIMD * 4;
    float* cw = (float*)p;                     p += (size_t)NEXP * T_TOK * 4;
    int* list = (int*)p;                       p += (size_t)NEXP * T_TOK * 4;
    int* tk_er = (int*)p;                      p += (size_t)T_TOK * TOPK * 4;
    float* tk_wv = (float*)p;                  p += (size_t)T_TOK * TOPK * 4;
    int* blk_cnt = (int*)p;                    p += (size_t)1024 * 16 * 4;
    int* blk_off = (int*)p;                    p += (size_t)1024 * 16 * 4;
    int* cnt = (int*)p;                        p += 256;
    int* offs = (int*)p;                       p += 256;
    int* table = (int*)p;                      p += 1024;
    if ((size_t)(p - (char*)d_ws) > ws_size) return;

    hipFuncSetAttribute((const void*)&gemm8p<0>, hipFuncAttributeMaxDynamicSharedMemorySize, 163840);
    hipFuncSetAttribute((const void*)&gemm8p<1>, hipFuncAttributeMaxDynamicSharedMemorySize, 163840);
    hipFuncSetAttribute((const void*)&gemm8p<2>, hipFuncAttributeMaxDynamicSharedMemorySize, 163840);
    hipFuncSetAttribute((const void*)&gemm8p<3>, hipFuncAttributeMaxDynamicSharedMemorySize, 163840);

    hipMemsetAsync(out, 0, (size_t)out_size * 4, stream);
    gwt_kernel<<<(NEXP * DIMD) / 256, 256, 0, stream>>>(gw, gwT);
    gate_kernel<<<T_TOK / 4, 256, 0, stream>>>(x, gwT, blk_cnt, tk_er, tk_wv);
    scan_kernel<<<1, 256, 0, stream>>>(blk_cnt, blk_off, cnt, offs, table);
    fill_kernel<<<T_TOK * TOPK / 256, 256, 0, stream>>>(tk_er, tk_wv, blk_off, list, cw);
    cvt_kernel<<<(T_TOK * DIMD / 8) / 256, 256, 0, stream>>>(x, xb);

    tq_kernel<1><<<dim3(NI / 32, DIMD / 32, NEXP), 256, 0, stream>>>(w1, upT, DIMD, NI, (size_t)2048 * DIMD);
    tq_kernel<2><<<dim3(NI / 32, DIMD / 32, NEXP), 256, 0, stream>>>(w3, upT, DIMD, NI, (size_t)2048 * DIMD);
    tq_kernel<1><<<dim3(NSH / 32, DIMD / 32, 1), 256, 0, stream>>>(ws1, upsT, DIMD, NSH, 0);
    tq_kernel<2><<<dim3(NSH / 32, DIMD / 32, 1), 256, 0, stream>>>(ws3, upsT, DIMD, NSH, 0);
    tq_kernel<0><<<dim3(DIMD / 32, NI / 32, NEXP), 256, 0, stream>>>(w2, w2T, NI, DIMD, (size_t)DIMD * NI);
    tq_kernel<0><<<dim3(DIMD / 32, NSH / 32, 1), 256, 0, stream>>>(ws2, ws2T, NSH, DIMD, 0);

    gemm8p<0><<<dim3(16, 16, 1), 512, 163840, stream>>>(
        xb, upsT, nullptr, nullptr, nullptr, nullptr, hs, nullptr, nullptr);
    gemm8p<2><<<dim3(8, 16, 2), 512, 163840, stream>>>(
        hs, ws2T, nullptr, nullptr, nullptr, nullptr, nullptr, out, nullptr);
    gemm8p<1><<<640, 512, 163840, stream>>>(
        xb, upT, cnt, offs, list, cw, hbuf, nullptr, table);
    gemm8p<3><<<640, 512, 163840, stream>>>(
        hbuf, w2T, cnt, offs, list, nullptr, nullptr, out, table);
}

// Round 9
// 708.012 us; speedup vs baseline: 1.2585x; 1.0105x over previous
//
#include <hip/hip_runtime.h>
#include <hip/hip_bf16.h>
#include <stdint.h>

#define T_TOK 4096
#define DIMD  2048
#define NEXP  16
#define TOPK  4
#define NI    1024
#define NSH   2048

typedef __attribute__((ext_vector_type(8))) short short8;
typedef __attribute__((ext_vector_type(4))) float f32x4;
typedef __attribute__((ext_vector_type(4))) unsigned short u16x4;

__device__ __forceinline__ unsigned short f2bf(float f) {
    union { float f; unsigned u; } v; v.f = f;
    return (unsigned short)((v.u + 0x7fffu + ((v.u >> 16) & 1u)) >> 16);
}

__device__ __forceinline__ void gload16(const void* g, void* l) {
    __builtin_amdgcn_global_load_lds(
        (const __attribute__((address_space(1))) void*)g,
        (__attribute__((address_space(3))) void*)l, 16, 0, 0);
}

// ---------------- gw transpose ----------------
__global__ __launch_bounds__(256) void gwt_kernel(const float* __restrict__ gw,
                                                  float* __restrict__ gwT) {
    int i = blockIdx.x * 256 + threadIdx.x;
    int d = i >> 4, e = i & 15;
    gwT[e * DIMD + d] = gw[i];
}

// ---------------- gate: scores + top-4, LDS-histogram routing ----------------
__global__ __launch_bounds__(256) void gate_kernel(const float* __restrict__ x,
                                                   const float* __restrict__ gwT,
                                                   int* __restrict__ blk_cnt,
                                                   int* __restrict__ tk_er,
                                                   float* __restrict__ tk_wv) {
    __shared__ int h[16];
    const int blk = blockIdx.x;
    const int t = blk * 4 + (threadIdx.x >> 6);
    const int lane = threadIdx.x & 63;
    if (threadIdx.x < 16) h[threadIdx.x] = 0;
    __syncthreads();

    const f32x4* xr = (const f32x4*)(x + (size_t)t * DIMD);
    f32x4 xv[8];
#pragma unroll
    for (int i = 0; i < 8; ++i) xv[i] = xr[i * 64 + lane];

    float acc[NEXP];
#pragma unroll
    for (int e = 0; e < NEXP; ++e) {
        const f32x4* gr = (const f32x4*)(gwT + e * DIMD);
        float s = 0.f;
#pragma unroll
        for (int i = 0; i < 8; ++i) {
            f32x4 gv = gr[i * 64 + lane];
            s += xv[i][0] * gv[0] + xv[i][1] * gv[1] +
                 xv[i][2] * gv[2] + xv[i][3] * gv[3];
        }
        acc[e] = s;
    }
#pragma unroll
    for (int e = 0; e < NEXP; ++e) {
        float v = acc[e];
#pragma unroll
        for (int off = 32; off; off >>= 1) v += __shfl_xor(v, off, 64);
        acc[e] = v;
    }
    float m = acc[0];
#pragma unroll
    for (int e = 1; e < NEXP; ++e) m = fmaxf(m, acc[e]);
    float s = 0.f;
#pragma unroll
    for (int e = 0; e < NEXP; ++e) { acc[e] = expf(acc[e] - m); s += acc[e]; }
    float inv = 1.f / s;
#pragma unroll
    for (int e = 0; e < NEXP; ++e) acc[e] *= inv;

    float w4[TOPK]; int i4[TOPK];
#pragma unroll
    for (int k = 0; k < TOPK; ++k) {
        float bv = -1.f; int be = 0;
#pragma unroll
        for (int e = 0; e < NEXP; ++e)
            if (acc[e] > bv) { bv = acc[e]; be = e; }
        w4[k] = bv; i4[k] = be;
#pragma unroll
        for (int e = 0; e < NEXP; ++e)
            if (e == be) acc[e] = -1.f;
    }

    if (lane == 0) {
        int r4[TOPK];
#pragma unroll
        for (int k = 0; k < TOPK; ++k) r4[k] = atomicAdd(&h[i4[k]], 1);
#pragma unroll
        for (int k = 0; k < TOPK; ++k) {
            tk_er[t * 4 + k] = (i4[k] << 20) | r4[k];
            tk_wv[t * 4 + k] = w4[k];
        }
    }
    __syncthreads();
    if (threadIdx.x < 16) blk_cnt[blk * 16 + threadIdx.x] = h[threadIdx.x];
}

// ---------------- hierarchical scan; slot table at BM=128 ----------------
__global__ __launch_bounds__(256) void scan_kernel(const int* __restrict__ blk_cnt,
                                                   int* __restrict__ blk_off,
                                                   int* __restrict__ cnt,
                                                   int* __restrict__ offs,
                                                   int* __restrict__ table) {
    __shared__ int gsum[16][17];
    __shared__ int gbase[16][17];
    __shared__ int csh[16];
    int tid = threadIdx.x;
    int e = tid >> 4, g = tid & 15;
    {
        int s = 0;
        for (int b = g * 64; b < g * 64 + 64; ++b) s += blk_cnt[b * 16 + e];
        gsum[e][g] = s;
    }
    __syncthreads();
    if (tid < 16) {
        int run = 0;
        for (int g2 = 0; g2 < 16; ++g2) { gbase[tid][g2] = run; run += gsum[tid][g2]; }
        csh[tid] = run;
        cnt[tid] = run;
    }
    __syncthreads();
    {
        int run = gbase[e][g];
        for (int b = g * 64; b < g * 64 + 64; ++b) {
            blk_off[b * 16 + e] = run;
            run += blk_cnt[b * 16 + e];
        }
    }
    if (tid == 0) {
        int o = 0;
        for (int e2 = 0; e2 < 16; ++e2) { offs[e2] = o; o += csh[e2]; }
        offs[NEXP] = o;
        int ns = 0;
        for (int e2 = 0; e2 < 16; ++e2)
            for (int rb = 0; rb < csh[e2]; rb += 128) {
                table[ns] = (e2 << 16) | rb; ++ns;
            }
        table[255] = ns;
    }
}

// ---------------- fill compacted expert lists ----------------
__global__ __launch_bounds__(256) void fill_kernel(const int* __restrict__ tk_er,
                                                   const float* __restrict__ tk_wv,
                                                   const int* __restrict__ blk_off,
                                                   int* __restrict__ list,
                                                   float* __restrict__ cw) {
    int i = blockIdx.x * 256 + threadIdx.x;
    int rec = tk_er[i];
    int e = rec >> 20, r = rec & 0xFFFFF;
    int t = i >> 2;
    int ro = blk_off[(t >> 2) * 16 + e] + r;
    list[e * T_TOK + ro] = t;
    cw[e * T_TOK + ro] = tk_wv[i];
}

// ---------------- x fp32 -> bf16 ----------------
__global__ __launch_bounds__(256) void cvt_kernel(const float* __restrict__ x,
                                                  unsigned short* __restrict__ xb) {
    int i = blockIdx.x * 256 + threadIdx.x;
    const f32x4* src = (const f32x4*)x;
    f32x4 a = src[i * 2 + 0];
    f32x4 b = src[i * 2 + 1];
    short8 o;
#pragma unroll
    for (int j = 0; j < 4; ++j) o[j] = (short)f2bf(a[j]);
#pragma unroll
    for (int j = 0; j < 4; ++j) o[4 + j] = (short)f2bf(b[j]);
    ((short8*)xb)[i] = o;
}

// ---------------- weight transpose + convert ----------------
template <int MODE>
__global__ __launch_bounds__(256) void tq_kernel(const float* __restrict__ src,
                                                 unsigned short* __restrict__ dst,
                                                 int K, int N, size_t dstStrideE) {
    int e = blockIdx.z;
    src += (size_t)e * K * N;
    dst += (size_t)e * dstStrideE;
    __shared__ unsigned short tile[32][36];
    int t = threadIdx.x;
    int k0 = blockIdx.y * 32, n0 = blockIdx.x * 32;
    {
        int row = t >> 3, c4 = (t & 7) * 4;
        f32x4 v = *(const f32x4*)(src + (size_t)(k0 + row) * N + n0 + c4);
#pragma unroll
        for (int j = 0; j < 4; ++j) tile[row][c4 + j] = f2bf(v[j]);
    }
    __syncthreads();
    {
        int nn = t >> 3, kc = (t & 7) * 4;
        int n = n0 + nn;
        int r = (MODE == 0) ? n : ((n >> 4) * 32 + (MODE == 2 ? 16 : 0) + (n & 15));
        u16x4 o;
#pragma unroll
        for (int j = 0; j < 4; ++j) o[j] = tile[kc + j][nn];
        *(u16x4*)(dst + (size_t)r * K + k0 + kc) = o;
    }
}

// ======== 128x256 GEMM, BK=32, 2 blocks/CU, A/B tri-buffered 2-ahead ========
// LDS 72KB/block: A 3x8KB at 0; B 3x16KB at 24576.
// Superrow swizzle: logical (r,k): s=r>>1, slot=((r&1)<<2)|(k>>3);
// phys byte = s*128 + ((slot ^ (s&7))<<4) + (k&7)*2. Stage pre-swizzles source.
template <int KIND>  // 0 shared-up, 1 routed-up, 2 shared-down splitK, 3 routed-down
__global__ __launch_bounds__(512, 4) void gemm8p(
    const unsigned short* __restrict__ A, const unsigned short* __restrict__ Ball,
    const int* __restrict__ cnt, const int* __restrict__ offs,
    const int* __restrict__ list, const float* __restrict__ cw,
    unsigned short* __restrict__ hout, float* __restrict__ fout,
    const int* __restrict__ table) {
    constexpr bool ROUTED = (KIND == 1 || KIND == 3);
    constexpr bool UP = (KIND <= 1);
    constexpr int K = (KIND <= 1) ? 2048 : 1024;
    constexpr int NT = K / 32;
    constexpr int ASTR = (KIND == 3) ? 1024 : 2048;
    constexpr int BSTR = (KIND == 3) ? 1024 : 2048;

    int bx, rb, e, M, obase;
    if constexpr (ROUTED) {
        int bid = blockIdx.x;
        int slot = bid >> 3;
        if (slot >= table[255]) return;
        bx = bid & 7;
        int pk = table[slot];
        e = pk >> 16;
        rb = pk & 0xFFFF;
        M = cnt[e];
        obase = offs[e];
    } else {
        bx = blockIdx.x; rb = blockIdx.y * 128; e = 0; M = T_TOK; obase = 0;
    }
    const int kb = (KIND == 2) ? blockIdx.z * 1024 : 0;
    const unsigned short* Bp = Ball +
        (KIND == 1 ? (size_t)e * 2048 * 2048 : KIND == 3 ? (size_t)e * 2048 * 1024 : 0);

    extern __shared__ char smem[];

    const int tid = threadIdx.x;
    const int lane = tid & 63, wid = tid >> 6;
    const int wm = wid >> 2, wn = wid & 3;          // wave tile 64x64
    const int fr = lane & 15, fq = lane >> 4;
    // fragment read offset (swizzled), same for every 16-row sub-tile
    const int offR = ((fr >> 1) << 7) + (((((fr & 1) << 2) | fq) ^ (fr >> 1)) << 4);
    const int d16 = tid * 16;

    // staging source maps (pre-swizzled global addresses)
    const unsigned short* pA;
    const unsigned short* pB0;
    const unsigned short* pB1;
    {
        int c = tid, s = c >> 3, sl = (c & 7) ^ (s & 7);
        int rA = 2 * s + (sl >> 2), kk = (sl & 3) * 8;
        int gr = rb + rA;
        int cr = (gr < M) ? gr : (M - 1);
        size_t arow;
        if (KIND == 1)      arow = (size_t)list[e * T_TOK + cr];
        else if (KIND == 3) arow = (size_t)(obase + cr);
        else                arow = (size_t)gr;
        pA = A + arow * ASTR + kb + kk;
    }
#pragma unroll
    for (int u = 0; u < 2; ++u) {
        int c = u * 512 + tid, s = c >> 3, sl = (c & 7) ^ (s & 7);
        int rB = 2 * s + (sl >> 2), kk = (sl & 3) * 8;
        const unsigned short* p = Bp + (size_t)(bx * 256 + rB) * BSTR + kb + kk;
        if (u == 0) pB0 = p; else pB1 = p;
    }

    f32x4 acc[4][4];
#pragma unroll
    for (int m = 0; m < 4; ++m)
#pragma unroll
        for (int n = 0; n < 4; ++n) acc[m][n] = (f32x4)0.f;

    // prologue: stage tiles 0,1 of A and B
    gload16(pA,      (void*)(smem + 0 + d16));
    gload16(pA + 32, (void*)(smem + 8192 + d16));
    gload16(pB0,      (void*)(smem + 24576 + d16));
    gload16(pB1,      (void*)(smem + 24576 + 8192 + d16));
    gload16(pB0 + 32, (void*)(smem + 24576 + 16384 + d16));
    gload16(pB1 + 32, (void*)(smem + 24576 + 16384 + 8192 + d16));
    pA += 64; pB0 += 64; pB1 += 64;   // next stage = tile 2
    asm volatile("s_waitcnt vmcnt(0)" ::: "memory");
    __builtin_amdgcn_s_barrier();

    int bA = 0, bA2 = 16384;          // A bufs 0,8192,16384
    int bB = 0, bB2 = 32768;          // B bufs 0,16384,32768 (+24576)
    for (int t = 0; t < NT; ++t) {
        short8 aF[4], bF[4];
#pragma unroll
        for (int m = 0; m < 4; ++m)
            aF[m] = *(const short8*)(smem + bA + wm * 4096 + m * 1024 + offR);
#pragma unroll
        for (int n = 0; n < 4; ++n)
            bF[n] = *(const short8*)(smem + 24576 + bB + wn * 4096 + n * 1024 + offR);
        const bool more = (t + 2 < NT);
        if (more) {
            gload16(pA, (void*)(smem + bA2 + d16));
            gload16(pB0, (void*)(smem + 24576 + bB2 + d16));
            gload16(pB1, (void*)(smem + 24576 + bB2 + 8192 + d16));
            pA += 32; pB0 += 32; pB1 += 32;
        }
        __builtin_amdgcn_s_setprio(1);
#pragma unroll
        for (int m = 0; m < 4; ++m)
#pragma unroll
            for (int n = 0; n < 4; ++n)
                acc[m][n] = __builtin_amdgcn_mfma_f32_16x16x32_bf16(aF[m], bF[n], acc[m][n], 0, 0, 0);
        __builtin_amdgcn_s_setprio(0);
        if (more) { asm volatile("s_waitcnt vmcnt(3)" ::: "memory"); }
        else      { asm volatile("s_waitcnt vmcnt(0)" ::: "memory"); }
        __builtin_amdgcn_s_barrier();
        bA = (bA == 16384) ? 0 : bA + 8192;
        bA2 = (bA2 == 16384) ? 0 : bA2 + 8192;
        bB = (bB == 32768) ? 0 : bB + 16384;
        bB2 = (bB2 == 32768) ? 0 : bB2 + 16384;
    }

    // epilogue
    if constexpr (UP) {
        constexpr int LDO = (KIND == 1) ? NI : NSH;
#pragma unroll
        for (int m = 0; m < 4; ++m)
#pragma unroll
            for (int q = 0; q < 4; ++q) {
                int gr = rb + wm * 64 + m * 16 + fq * 4 + q;
                if (gr < M) {
                    float coef = 1.f;
                    if constexpr (KIND == 1) coef = cw[e * T_TOK + gr];
                    size_t orow = (size_t)(obase + gr) * LDO;
#pragma unroll
                    for (int nfp = 0; nfp < 2; ++nfp) {
                        float c1 = acc[m][2 * nfp][q], c3 = acc[m][2 * nfp + 1][q];
                        float h = c1 / (1.f + __expf(-c1)) * c3 * coef;
                        int ncol = (bx * 8 + wn * 2 + nfp) * 16 + fr;
                        hout[orow + ncol] = f2bf(h);
                    }
                }
            }
    } else {
#pragma unroll
        for (int m = 0; m < 4; ++m)
#pragma unroll
            for (int q = 0; q < 4; ++q) {
                int gr = rb + wm * 64 + m * 16 + fq * 4 + q;
                if (gr < M) {
                    int orow = (KIND == 3) ? list[e * T_TOK + gr] : gr;
#pragma unroll
                    for (int nf = 0; nf < 4; ++nf) {
                        int col = bx * 256 + wn * 64 + nf * 16 + fr;
                        atomicAdd(fout + (size_t)orow * DIMD + col, acc[m][nf][q]);
                    }
                }
            }
    }
}

extern "C" void kernel_launch(void* const* d_in, const int* in_sizes, int n_in,
                              void* d_out, int out_size, void* d_ws, size_t ws_size,
                              hipStream_t stream) {
    const float* x   = (const float*)d_in[0];
    const float* gw  = (const float*)d_in[1];
    const float* w1  = (const float*)d_in[2];
    const float* w2  = (const float*)d_in[3];
    const float* w3  = (const float*)d_in[4];
    const float* ws1 = (const float*)d_in[5];
    const float* ws2 = (const float*)d_in[6];
    const float* ws3 = (const float*)d_in[7];
    float* out = (float*)d_out;

    char* p = (char*)d_ws;
    unsigned short* xb   = (unsigned short*)p; p += (size_t)T_TOK * DIMD * 2;
    unsigned short* hs   = (unsigned short*)p; p += (size_t)T_TOK * NSH * 2;
    unsigned short* hbuf = (unsigned short*)p; p += (size_t)T_TOK * TOPK * NI * 2;
    unsigned short* upT  = (unsigned short*)p; p += (size_t)NEXP * 2048 * DIMD * 2;
    unsigned short* w2T  = (unsigned short*)p; p += (size_t)NEXP * DIMD * NI * 2;
    unsigned short* upsT = (unsigned short*)p; p += (size_t)2 * NSH * DIMD * 2;
    unsigned short* ws2T = (unsigned short*)p; p += (size_t)DIMD * NSH * 2;
    float* gwT = (float*)p;                    p += (size_t)NEXP * DIMD * 4;
    float* cw = (float*)p;                     p += (size_t)NEXP * T_TOK * 4;
    int* list = (int*)p;                       p += (size_t)NEXP * T_TOK * 4;
    int* tk_er = (int*)p;                      p += (size_t)T_TOK * TOPK * 4;
    float* tk_wv = (float*)p;                  p += (size_t)T_TOK * TOPK * 4;
    int* blk_cnt = (int*)p;                    p += (size_t)1024 * 16 * 4;
    int* blk_off = (int*)p;                    p += (size_t)1024 * 16 * 4;
    int* cnt = (int*)p;                        p += 256;
    int* offs = (int*)p;                       p += 256;
    int* table = (int*)p;                      p += 1024;
    if ((size_t)(p - (char*)d_ws) > ws_size) return;

    hipFuncSetAttribute((const void*)&gemm8p<0>, hipFuncAttributeMaxDynamicSharedMemorySize, 73728);
    hipFuncSetAttribute((const void*)&gemm8p<1>, hipFuncAttributeMaxDynamicSharedMemorySize, 73728);
    hipFuncSetAttribute((const void*)&gemm8p<2>, hipFuncAttributeMaxDynamicSharedMemorySize, 73728);
    hipFuncSetAttribute((const void*)&gemm8p<3>, hipFuncAttributeMaxDynamicSharedMemorySize, 73728);

    hipMemsetAsync(out, 0, (size_t)out_size * 4, stream);
    gwt_kernel<<<(NEXP * DIMD) / 256, 256, 0, stream>>>(gw, gwT);
    gate_kernel<<<T_TOK / 4, 256, 0, stream>>>(x, gwT, blk_cnt, tk_er, tk_wv);
    scan_kernel<<<1, 256, 0, stream>>>(blk_cnt, blk_off, cnt, offs, table);
    fill_kernel<<<T_TOK * TOPK / 256, 256, 0, stream>>>(tk_er, tk_wv, blk_off, list, cw);
    cvt_kernel<<<(T_TOK * DIMD / 8) / 256, 256, 0, stream>>>(x, xb);

    tq_kernel<1><<<dim3(NI / 32, DIMD / 32, NEXP), 256, 0, stream>>>(w1, upT, DIMD, NI, (size_t)2048 * DIMD);
    tq_kernel<2><<<dim3(NI / 32, DIMD / 32, NEXP), 256, 0, stream>>>(w3, upT, DIMD, NI, (size_t)2048 * DIMD);
    tq_kernel<1><<<dim3(NSH / 32, DIMD / 32, 1), 256, 0, stream>>>(ws1, upsT, DIMD, NSH, 0);
    tq_kernel<2><<<dim3(NSH / 32, DIMD / 32, 1), 256, 0, stream>>>(ws3, upsT, DIMD, NSH, 0);
    tq_kernel<0><<<dim3(DIMD / 32, NI / 32, NEXP), 256, 0, stream>>>(w2, w2T, NI, DIMD, (size_t)DIMD * NI);
    tq_kernel<0><<<dim3(DIMD / 32, NSH / 32, 1), 256, 0, stream>>>(ws2, ws2T, NSH, DIMD, 0);

    // shared-up: 16 x 32 = 512 units (one full resident round at 2 blocks/CU)
    gemm8p<0><<<dim3(16, 32, 1), 512, 73728, stream>>>(
        xb, upsT, nullptr, nullptr, nullptr, nullptr, hs, nullptr, nullptr);
    // shared-down: split-K=2, 8 x 32 x 2 = 512 units
    gemm8p<2><<<dim3(8, 32, 2), 512, 73728, stream>>>(
        hs, ws2T, nullptr, nullptr, nullptr, nullptr, nullptr, out, nullptr);
    // routed: slots(BM=128) x 8 N-tiles; max 144*8=1152
    gemm8p<1><<<1152, 512, 73728, stream>>>(
        xb, upT, cnt, offs, list, cw, hbuf, nullptr, table);
    gemm8p<3><<<1152, 512, 73728, stream>>>(
        hbuf, w2T, cnt, offs, list, nullptr, nullptr, out, table);
}